// Round 10
// baseline (470.361 us; speedup 1.0000x reference)
//
#include <hip/hip_runtime.h>
#include <math.h>

#define NB 4096
#define NH 3
#define NK 32768
#define ND 128
#define KE 384           // B extended K: [wh(128) | wl(128) | wh(128)]
#define KA 256           // A stored K: [rh(128) | rl(128)]  (hi panel deduped)
#define RB 64            // rows per block
#define CS 16            // column splits (2 per XCD)
#define CPB (NK / CS)    // 2048 cols per block
#define CI 256           // cols per col-iteration (4 waves x 64)
#define NCI (CPB / CI)   // 8 col-iterations per block

typedef _Float16 half8_t __attribute__((ext_vector_type(8)));
typedef _Float16 half2_t __attribute__((ext_vector_type(2)));
typedef float f32x4 __attribute__((ext_vector_type(4)));
typedef __attribute__((address_space(1))) const unsigned int gu32_t;
typedef __attribute__((address_space(3))) unsigned int lu32_t;

// ---------------------------------------------------------------------------
// init: resid = inputs, quantized = 0, loss = 0, rr = sum(resid^2), Aext row.
__global__ __launch_bounds__(64) void init_kernel(const float* __restrict__ inp,
                                                  float* __restrict__ resid,
                                                  float* __restrict__ rr,
                                                  float* __restrict__ out,
                                                  _Float16* __restrict__ Aext) {
  int row = blockIdx.x;
  int lane = threadIdx.x;
  const float2* ip = (const float2*)(inp + row * ND);
  float2 v = ip[lane];
  ((float2*)(resid + row * ND))[lane] = v;
  ((float2*)(out + NB + row * ND))[lane] = make_float2(0.f, 0.f);
  if (lane == 0) out[row] = 0.f; // loss
  _Float16 h0 = (_Float16)v.x, h1 = (_Float16)v.y;
  _Float16 l0 = (_Float16)(v.x - (float)h0), l1 = (_Float16)(v.y - (float)h1);
  half2_t h = {h0, h1}, l = {l0, l1};
  _Float16* base = Aext + (size_t)row * KA;
  *(half2_t*)(base + 2 * lane) = h;       // rh
  *(half2_t*)(base + 128 + 2 * lane) = l; // rl
  float s = v.x * v.x + v.y * v.y;
  #pragma unroll
  for (int m = 32; m; m >>= 1) s += __shfl_xor(s, m, 64);
  if (lane == 0) rr[row] = s;
}

// ---------------------------------------------------------------------------
// norms[row] = sum(W[row]^2) for all H*K rows (one wave per row), fp32 exact
__global__ __launch_bounds__(256) void norms_kernel(const float* __restrict__ emb,
                                                    float* __restrict__ norms) {
  int row = blockIdx.x * 4 + (threadIdx.x >> 6);
  int lane = threadIdx.x & 63;
  const float2* wp = (const float2*)(emb + (size_t)row * ND);
  float2 v = wp[lane];
  float s = v.x * v.x + v.y * v.y;
  #pragma unroll
  for (int m = 32; m; m >>= 1) s += __shfl_xor(s, m, 64);
  if (lane == 0) norms[row] = s;
}

// ---------------------------------------------------------------------------
// fp32 -> (hi,lo) fp16 split into kstep-major fragment layout:
//   Bext f16 offset = col64*24576 + ks*2048 + tn*512 + klo*128 + n_lo*8 + j
// where col64 = n>>6, tn = (n>>4)&3, ks = kstep (12 of K=32 each),
// klo = (k>>3)&3, j = k&7. The 4 tn-fragments of one kstep are contiguous
// (byte offsets 0/1024/2048/3072 -> all 13-bit-imm addressable), so the
// score kernel needs ONE 32-bit voffset per kstep (saddr+imm form).
// ks 0..3 = wh(k0..127), 4..7 = wl, 8..11 = wh duplicate.
__global__ __launch_bounds__(256) void split_w_kernel(const float* __restrict__ W,
                                                      _Float16* __restrict__ Bext) {
  const int cg = blockIdx.x;      // col group 0..2047 (16 cols each)
  const int n_lo = threadIdx.x & 15;
  const int c = threadIdx.x >> 4; // 8-element k-chunk 0..15 (k = c*8..c*8+7)
  const int n = cg * 16 + n_lo;

  const float4* wp = (const float4*)(W + (size_t)n * ND + c * 8);
  float4 v0 = wp[0], v1 = wp[1];
  float xv[8] = {v0.x, v0.y, v0.z, v0.w, v1.x, v1.y, v1.z, v1.w};
  half8_t h, l;
  #pragma unroll
  for (int j = 0; j < 8; ++j) {
    _Float16 hh = (_Float16)xv[j];
    h[j] = hh;
    l[j] = (_Float16)(xv[j] - (float)hh);
  }
  const int ks0 = c >> 2;  // kstep within a 128-k panel
  const int klo = c & 3;   // 8-chunk within the 32-k step
  _Float16* base = Bext + (size_t)(cg >> 2) * 24576 + (cg & 3) * 512 + klo * 128 + n_lo * 8;
  *(half8_t*)(base + ks0 * 2048) = h;        // wh  (ks 0..3)
  *(half8_t*)(base + (4 + ks0) * 2048) = l;  // wl  (ks 4..7)
  *(half8_t*)(base + (8 + ks0) * 2048) = h;  // wh  (ks 8..11, duplicate)
}

// ---------------------------------------------------------------------------
// Barrier-free score kernel. 64-row block, A panel [rh|rl] (32 KB) in LDS
// staged once; 4 waves each own a 64x64 col tile, marching DESCENDING over
// 2048 cols (8 iters). B fragments: kstep-major layout -> one 32-bit
// voffset per kstep + imm offsets (cheap addressing, few live VGPRs).
// A-panel dedup: ksteps 4..7 (B=wl) reuse rh via ka = (ks&3)|((ks>>1)&4).
// Running argmax in registers: descending order + ">=" == first-index tie.
// bid&15 = col-split; two 1.5 MB B slices per XCD's L2.
// launch_bounds (256,2): min-waves=3 squeezes the allocator into spills
// (R6). Residency is set by ACTUAL reg usage; goal here is total
// (VGPR+AGPR) <= ~170 so HW gives 3 waves/SIMD on its own.
__global__ __launch_bounds__(256, 2) void score_mfma_kernel(
    const _Float16* __restrict__ Aext, const _Float16* __restrict__ Bext,
    const float* __restrict__ rr, const float* __restrict__ normh,
    float* __restrict__ partial_s, int* __restrict__ partial_i) {
  __shared__ __align__(16) _Float16 Ash[RB * KA]; // 32 KB

  const int bid = blockIdx.x;
  const int cs = bid & 15;
  const int rowb = bid >> 4;
  const int rowBase = rowb * RB;
  const int colBase0 = cs * CPB;

  const int tid = threadIdx.x;
  const int lane = tid & 63;
  const int wn = tid >> 6; // wave = col group 0..3
  const int l15 = lane & 15;
  const int q = lane >> 4;

  // ---- stage A panel [rh|rl] (once) ----
  {
    const int mrow = lane >> 3;             // 0..7 within 8-row group
    const int cg = (lane & 7) ^ (mrow & 7); // chunk this lane fetches
    #pragma unroll
    for (int i = 0; i < 8; ++i) {
      int wc = wn * 8 + i; // 0..31 wave-chunks (1 KB each)
      int p = wc >> 3;     // panel 0..3 (64 k each)
      int m0 = (wc & 7) * 8;
      const _Float16* gA = Aext + (size_t)(rowBase + m0 + mrow) * KA + p * 64 + cg * 8;
      __builtin_amdgcn_global_load_lds((gu32_t*)gA, (lu32_t*)&Ash[(p * 64 + m0) * 64], 16, 0, 0);
    }
  }

  // per-lane A-fragment LDS byte addresses (2 kstep parities x 4 m-tiles)
  int aaddr[2][4];
  #pragma unroll
  for (int par = 0; par < 2; ++par)
    #pragma unroll
    for (int mt = 0; mt < 4; ++mt) {
      int m = mt * 16 + l15;
      int slot = (par * 4 + q) ^ (m & 7);
      aaddr[par][mt] = (m * 8 + slot) * 16; // bytes
    }

  // per-lane rr values (row = mt*16 + q*4 + reg)
  float rv[16];
  #pragma unroll
  for (int mt = 0; mt < 4; ++mt)
    #pragma unroll
    for (int reg = 0; reg < 4; ++reg)
      rv[mt * 4 + reg] = rr[rowBase + mt * 16 + q * 4 + reg];

  float bs[16];
  int bi[16];
  #pragma unroll
  for (int t = 0; t < 16; ++t) { bs[t] = -INFINITY; bi[t] = 0x7fffffff; }

  __syncthreads(); // the only barrier before the epilogue

  #pragma unroll 1
  for (int ci = NCI - 1; ci >= 0; --ci) {
    const int ncol = colBase0 + ci * CI + wn * 64;
    // 32-bit f16-index against uniform Bext base (saddr + voffset + imm)
    const unsigned int boff = (unsigned int)(ncol >> 6) * 24576u + (unsigned int)lane * 8u;

    f32x4 acc[4][4];
    #pragma unroll
    for (int i = 0; i < 4; ++i)
      #pragma unroll
      for (int j = 0; j < 4; ++j) acc[i][j] = (f32x4){0.f, 0.f, 0.f, 0.f};

    #pragma unroll 4
    for (int ks = 0; ks < 12; ++ks) {
      half8_t bf[4];
      #pragma unroll
      for (int tn = 0; tn < 4; ++tn)
        bf[tn] = *(const half8_t*)(Bext + boff + (unsigned int)(ks * 2048 + tn * 512));
      // A k-index: ks 0..3 -> rh, 4..7 -> rh (dedup), 8..11 -> rl
      const int ka = (ks & 3) | ((ks >> 1) & 4); // 0..3,0..3,4..7
      half8_t af[4];
      #pragma unroll
      for (int mt = 0; mt < 4; ++mt)
        af[mt] = *(const half8_t*)((const char*)Ash + aaddr[ka & 1][mt] + (ka >> 1) * 8192);
      #pragma unroll
      for (int mt = 0; mt < 4; ++mt)
        #pragma unroll
        for (int tn = 0; tn < 4; ++tn)
          acc[mt][tn] = __builtin_amdgcn_mfma_f32_16x16x32_f16(af[mt], bf[tn], acc[mt][tn], 0, 0, 0);
    }

    // fold into running argmax; tn DESCENDING + ci descending => cols visited
    // in strictly decreasing order, so `>=` keeps the lowest index on ties.
    #pragma unroll
    for (int tn = 3; tn >= 0; --tn) {
      float nw = normh[ncol + tn * 16 + l15];
      int cidx = ncol + tn * 16 + l15;
      #pragma unroll
      for (int mt = 0; mt < 4; ++mt) {
        #pragma unroll
        for (int reg = 0; reg < 4; ++reg) {
          const int s = mt * 4 + reg;
          float t1 = rv[s] + nw;                       // fl(rr + |w|^2), as ref
          float v = fmaf(2.0f, acc[mt][tn][reg], -t1); // == fl(2*acc - t1)
          if (v >= bs[s]) { bs[s] = v; bi[s] = cidx; }
        }
      }
    }
  }

  // ---- block argmax reduction (overlay scratch on Ash) ----
  __syncthreads(); // all LDS A-reads complete
  float* red_s = (float*)Ash;      // [64][4]
  int* red_i = (int*)Ash + RB * 4; // [64][4]
  #pragma unroll
  for (int t = 0; t < 16; ++t) {
    float s = bs[t];
    int ii = bi[t];
    #pragma unroll
    for (int mask = 1; mask <= 8; mask <<= 1) {
      float os = __shfl_xor(s, mask, 64);
      int oi = __shfl_xor(ii, mask, 64);
      if (os > s || (os == s && oi < ii)) { s = os; ii = oi; }
    }
    if (l15 == 0) {
      int rloc = (t >> 2) * 16 + q * 4 + (t & 3); // mt*16 + q*4 + reg
      red_s[rloc * 4 + wn] = s;
      red_i[rloc * 4 + wn] = ii;
    }
  }
  __syncthreads();
  if (tid < RB) {
    float s0 = red_s[tid * 4];
    int i0 = red_i[tid * 4];
    #pragma unroll
    for (int x = 1; x < 4; ++x) {
      float sx = red_s[tid * 4 + x];
      int ix = red_i[tid * 4 + x];
      if (sx > s0 || (sx == s0 && ix < i0)) { s0 = sx; i0 = ix; }
    }
    partial_s[(size_t)(rowBase + tid) * CS + cs] = s0;
    partial_i[(size_t)(rowBase + tid) * CS + cs] = i0;
  }
}

// ---------------------------------------------------------------------------
// Combine col-split partials -> code; resid -= W[c]; quantized += W[c];
// new rr; Aext row for next head.
__global__ __launch_bounds__(64) void reduce_update_kernel(const float* __restrict__ embh,
                                                           float* __restrict__ resid,
                                                           float* __restrict__ rr,
                                                           const float* __restrict__ ps,
                                                           const int* __restrict__ pi,
                                                           float* __restrict__ out,
                                                           _Float16* __restrict__ Aext, int h) {
  int row = blockIdx.x;
  int lane = threadIdx.x;
  float bs = -INFINITY;
  int bi = 0x7fffffff;
  if (lane < CS) {
    bs = ps[(size_t)row * CS + lane];
    bi = pi[(size_t)row * CS + lane];
  }
  #pragma unroll
  for (int m = 8; m; m >>= 1) {
    float os = __shfl_xor(bs, m, 64);
    int oi = __shfl_xor(bi, m, 64);
    if (os > bs || (os == bs && oi < bi)) { bs = os; bi = oi; }
  }
  int c = __shfl(bi, 0, 64);
  if (lane == 0) out[NB + NB * ND + row * NH + h] = (float)c; // codes as f32

  const float* wv = embh + (size_t)c * ND;
  float q0 = wv[lane], q1 = wv[lane + 64];
  float r0 = resid[row * ND + lane] - q0;
  float r1 = resid[row * ND + lane + 64] - q1;
  resid[row * ND + lane] = r0;
  resid[row * ND + lane + 64] = r1;
  out[NB + row * ND + lane] += q0;
  out[NB + row * ND + lane + 64] += q1;

  // Aext row for the next head (harmless extra work on the last head)
  _Float16 h0 = (_Float16)r0, l0 = (_Float16)(r0 - (float)h0);
  _Float16 h1 = (_Float16)r1, l1 = (_Float16)(r1 - (float)h1);
  _Float16* ab = Aext + (size_t)row * KA;
  ab[lane] = h0;       ab[lane + 64] = h1;       // rh
  ab[128 + lane] = l0; ab[128 + lane + 64] = l1; // rl

  float s = r0 * r0 + r1 * r1;
  #pragma unroll
  for (int m = 32; m; m >>= 1) s += __shfl_xor(s, m, 64);
  if (lane == 0) rr[row] = s;
}

// ---------------------------------------------------------------------------
extern "C" void kernel_launch(void* const* d_in, const int* in_sizes, int n_in,
                              void* d_out, int out_size, void* d_ws, size_t ws_size,
                              hipStream_t stream) {
  const float* inp = (const float*)d_in[0]; // (4096,1,128)
  const float* emb = (const float*)d_in[1]; // (3,32768,128)
  float* out = (float*)d_out;               // loss | quantized | codes

  float* resid = (float*)d_ws;                        // NB*ND f32
  float* rr = resid + NB * ND;                        // NB
  float* norms = rr + NB;                             // NH*NK
  float* ps = norms + NH * NK;                        // NB*CS f32
  int* pi = (int*)(ps + (size_t)NB * CS);             // NB*CS i32
  _Float16* Aext = (_Float16*)(pi + (size_t)NB * CS); // NB*KA f16
  _Float16* Bext = Aext + (size_t)NB * KA;            // NK*KE f16 (kstep-major fragments)

  hipLaunchKernelGGL(init_kernel, dim3(NB), dim3(64), 0, stream, inp, resid, rr, out, Aext);
  hipLaunchKernelGGL(norms_kernel, dim3(NH * NK / 4), dim3(256), 0, stream, emb, norms);
  for (int h = 0; h < NH; ++h) {
    hipLaunchKernelGGL(split_w_kernel, dim3(NK / 16), dim3(256), 0, stream,
                       emb + (size_t)h * NK * ND, Bext);
    hipLaunchKernelGGL(score_mfma_kernel, dim3((NB / RB) * CS), dim3(256), 0, stream,
                       Aext, Bext, rr, norms + (size_t)h * NK, ps, pi);
    hipLaunchKernelGGL(reduce_update_kernel, dim3(NB), dim3(64), 0, stream,
                       emb + (size_t)h * NK * ND, resid, rr, ps, pi, out, Aext, h);
  }
}

// Round 11
// 405.644 us; speedup vs baseline: 1.1595x; 1.1595x over previous
//
#include <hip/hip_runtime.h>
#include <math.h>

#define NB 4096
#define NH 3
#define NK 32768
#define ND 128
#define KA 256           // A stored K: [rh(128) | rl(128)]
#define KB 256           // B stored K: [wh(128) | wl(128)]  (dedup: wh read twice via regs)
#define RB 64            // rows per block
#define CS 16            // column splits (2 per XCD)
#define CPB (NK / CS)    // 2048 cols per block
#define CI 256           // cols per col-iteration (4 waves x 64)
#define NCI (CPB / CI)   // 8 col-iterations per block

typedef _Float16 half8_t __attribute__((ext_vector_type(8)));
typedef _Float16 half2_t __attribute__((ext_vector_type(2)));
typedef float f32x4 __attribute__((ext_vector_type(4)));
typedef __attribute__((address_space(1))) const unsigned int gu32_t;
typedef __attribute__((address_space(3))) unsigned int lu32_t;

// ---------------------------------------------------------------------------
// init: resid = inputs, quantized = 0, loss = 0, rr = sum(resid^2), Aext row.
__global__ __launch_bounds__(64) void init_kernel(const float* __restrict__ inp,
                                                  float* __restrict__ resid,
                                                  float* __restrict__ rr,
                                                  float* __restrict__ out,
                                                  _Float16* __restrict__ Aext) {
  int row = blockIdx.x;
  int lane = threadIdx.x;
  const float2* ip = (const float2*)(inp + row * ND);
  float2 v = ip[lane];
  ((float2*)(resid + row * ND))[lane] = v;
  ((float2*)(out + NB + row * ND))[lane] = make_float2(0.f, 0.f);
  if (lane == 0) out[row] = 0.f; // loss
  _Float16 h0 = (_Float16)v.x, h1 = (_Float16)v.y;
  _Float16 l0 = (_Float16)(v.x - (float)h0), l1 = (_Float16)(v.y - (float)h1);
  half2_t h = {h0, h1}, l = {l0, l1};
  _Float16* base = Aext + (size_t)row * KA;
  *(half2_t*)(base + 2 * lane) = h;       // rh
  *(half2_t*)(base + 128 + 2 * lane) = l; // rl
  float s = v.x * v.x + v.y * v.y;
  #pragma unroll
  for (int m = 32; m; m >>= 1) s += __shfl_xor(s, m, 64);
  if (lane == 0) rr[row] = s;
}

// ---------------------------------------------------------------------------
// norms[row] = sum(W[row]^2) for all H*K rows (one wave per row), fp32 exact
__global__ __launch_bounds__(256) void norms_kernel(const float* __restrict__ emb,
                                                    float* __restrict__ norms) {
  int row = blockIdx.x * 4 + (threadIdx.x >> 6);
  int lane = threadIdx.x & 63;
  const float2* wp = (const float2*)(emb + (size_t)row * ND);
  float2 v = wp[lane];
  float s = v.x * v.x + v.y * v.y;
  #pragma unroll
  for (int m = 32; m; m >>= 1) s += __shfl_xor(s, m, 64);
  if (lane == 0) norms[row] = s;
}

// ---------------------------------------------------------------------------
// fp32 -> (hi,lo) fp16 split, ALL heads at once (emb is static), into
// kstep-major fragment layout WITHOUT the wh duplicate:
//   f16 offset = head*NK*KB + col64*16384 + ks*2048 + tn*512 + klo*128 + n_lo*8 + j
// ks 0..3 = wh chunks (k 0..127), ks 4..7 = wl chunks. A wave's 4 tn
// fragments of one ks are at byte offsets 0/1024/2048/3072 (imm-addressable).
__global__ __launch_bounds__(256) void split_w_all_kernel(const float* __restrict__ emb,
                                                          _Float16* __restrict__ Bext) {
  const int head = blockIdx.x >> 11;      // 0..2
  const int cg = blockIdx.x & 2047;       // col group 0..2047 (16 cols each)
  const int n_lo = threadIdx.x & 15;
  const int c = threadIdx.x >> 4;         // 8-elem k-chunk 0..15 (k = c*8..)
  const int n = cg * 16 + n_lo;

  const float4* wp = (const float4*)(emb + (size_t)head * NK * ND + (size_t)n * ND + c * 8);
  float4 v0 = wp[0], v1 = wp[1];
  float xv[8] = {v0.x, v0.y, v0.z, v0.w, v1.x, v1.y, v1.z, v1.w};
  half8_t h, l;
  #pragma unroll
  for (int j = 0; j < 8; ++j) {
    _Float16 hh = (_Float16)xv[j];
    h[j] = hh;
    l[j] = (_Float16)(xv[j] - (float)hh);
  }
  const int ks0 = c >> 2; // 32-k chunk 0..3
  const int klo = c & 3;  // 8-chunk within the 32-k step
  _Float16* base = Bext + (size_t)head * NK * KB + (size_t)(cg >> 2) * 16384 +
                   (cg & 3) * 512 + klo * 128 + n_lo * 8;
  *(half8_t*)(base + ks0 * 2048) = h;       // wh  (ks 0..3)
  *(half8_t*)(base + (4 + ks0) * 2048) = l; // wl  (ks 4..7)
}

// ---------------------------------------------------------------------------
// Barrier-free score kernel. 64-row block, A panel [rh|rl] (32 KB) in LDS
// staged once; 4 waves each own a 64x64 col tile, marching DESCENDING over
// 2048 cols (8 iters). B dedup: per 32-k chunk kc, load 4 wh + 4 wl
// fragments ONCE; wh feeds TWO MFMA sets (A=rh and A=rl), wl feeds one
// (A=rh) -> L2 B-traffic cut 33% vs the extended-K stream (the R10 lever:
// per-CU L2 leg 47 -> 31 us under the 50 us MFMA floor).
// Running argmax in registers: descending order + ">=" == first-index tie.
// bid&15 = col-split; 1 MB B slice x2 per XCD's L2. launch_bounds (256,2):
// min-waves=3 squeezes the allocator into spills (R6 evidence).
__global__ __launch_bounds__(256, 2) void score_mfma_kernel(
    const _Float16* __restrict__ Aext, const _Float16* __restrict__ Bext,
    const float* __restrict__ rr, const float* __restrict__ normh,
    float* __restrict__ partial_s, int* __restrict__ partial_i) {
  __shared__ __align__(16) _Float16 Ash[RB * KA]; // 32 KB

  const int bid = blockIdx.x;
  const int cs = bid & 15;
  const int rowb = bid >> 4;
  const int rowBase = rowb * RB;
  const int colBase0 = cs * CPB;

  const int tid = threadIdx.x;
  const int lane = tid & 63;
  const int wn = tid >> 6; // wave = col group 0..3
  const int l15 = lane & 15;
  const int q = lane >> 4;

  // ---- stage A panel [rh|rl] (once) ----
  {
    const int mrow = lane >> 3;             // 0..7 within 8-row group
    const int cg = (lane & 7) ^ (mrow & 7); // chunk this lane fetches
    #pragma unroll
    for (int i = 0; i < 8; ++i) {
      int wc = wn * 8 + i; // 0..31 wave-chunks (1 KB each)
      int p = wc >> 3;     // panel 0..3 (64 k each)
      int m0 = (wc & 7) * 8;
      const _Float16* gA = Aext + (size_t)(rowBase + m0 + mrow) * KA + p * 64 + cg * 8;
      __builtin_amdgcn_global_load_lds((gu32_t*)gA, (lu32_t*)&Ash[(p * 64 + m0) * 64], 16, 0, 0);
    }
  }

  // per-lane A-fragment LDS byte addresses (2 kc parities x 4 m-tiles)
  int aaddr[2][4];
  #pragma unroll
  for (int par = 0; par < 2; ++par)
    #pragma unroll
    for (int mt = 0; mt < 4; ++mt) {
      int m = mt * 16 + l15;
      int slot = (par * 4 + q) ^ (m & 7);
      aaddr[par][mt] = (m * 8 + slot) * 16; // bytes
    }

  // per-lane rr values (row = mt*16 + q*4 + reg)
  float rv[16];
  #pragma unroll
  for (int mt = 0; mt < 4; ++mt)
    #pragma unroll
    for (int reg = 0; reg < 4; ++reg)
      rv[mt * 4 + reg] = rr[rowBase + mt * 16 + q * 4 + reg];

  float bs[16];
  int bi[16];
  #pragma unroll
  for (int t = 0; t < 16; ++t) { bs[t] = -INFINITY; bi[t] = 0x7fffffff; }

  __syncthreads(); // the only barrier before the epilogue

  #pragma unroll 1
  for (int ci = NCI - 1; ci >= 0; --ci) {
    const int ncol = colBase0 + ci * CI + wn * 64;
    // 32-bit f16-index vs uniform Bext base (saddr + voffset + imm)
    const unsigned int boff = (unsigned int)(ncol >> 6) * 16384u + (unsigned int)lane * 8u;

    f32x4 acc[4][4];
    #pragma unroll
    for (int i = 0; i < 4; ++i)
      #pragma unroll
      for (int j = 0; j < 4; ++j) acc[i][j] = (f32x4){0.f, 0.f, 0.f, 0.f};

    #pragma unroll 2
    for (int kc = 0; kc < 4; ++kc) {
      half8_t bh[4], bl[4];
      #pragma unroll
      for (int tn = 0; tn < 4; ++tn) {
        bh[tn] = *(const half8_t*)(Bext + boff + (unsigned int)(kc * 2048 + tn * 512));
        bl[tn] = *(const half8_t*)(Bext + boff + (unsigned int)((4 + kc) * 2048 + tn * 512));
      }
      const int par = kc & 1, p = kc >> 1;
      half8_t afh[4], afl[4];
      #pragma unroll
      for (int mt = 0; mt < 4; ++mt) {
        afh[mt] = *(const half8_t*)((const char*)Ash + aaddr[par][mt] + p * 8192);
        afl[mt] = *(const half8_t*)((const char*)Ash + aaddr[par][mt] + 16384 + p * 8192);
      }
      #pragma unroll
      for (int mt = 0; mt < 4; ++mt)
        #pragma unroll
        for (int tn = 0; tn < 4; ++tn)
          acc[mt][tn] = __builtin_amdgcn_mfma_f32_16x16x32_f16(afh[mt], bh[tn], acc[mt][tn], 0, 0, 0);
      #pragma unroll
      for (int mt = 0; mt < 4; ++mt)
        #pragma unroll
        for (int tn = 0; tn < 4; ++tn)
          acc[mt][tn] = __builtin_amdgcn_mfma_f32_16x16x32_f16(afl[mt], bh[tn], acc[mt][tn], 0, 0, 0);
      #pragma unroll
      for (int mt = 0; mt < 4; ++mt)
        #pragma unroll
        for (int tn = 0; tn < 4; ++tn)
          acc[mt][tn] = __builtin_amdgcn_mfma_f32_16x16x32_f16(afh[mt], bl[tn], acc[mt][tn], 0, 0, 0);
    }

    // fold into running argmax; tn DESCENDING + ci descending => cols visited
    // in strictly decreasing order, so `>=` keeps the lowest index on ties.
    #pragma unroll
    for (int tn = 3; tn >= 0; --tn) {
      float nw = normh[ncol + tn * 16 + l15];
      int cidx = ncol + tn * 16 + l15;
      #pragma unroll
      for (int mt = 0; mt < 4; ++mt) {
        #pragma unroll
        for (int reg = 0; reg < 4; ++reg) {
          const int s = mt * 4 + reg;
          float t1 = rv[s] + nw;                       // fl(rr + |w|^2), as ref
          float v = fmaf(2.0f, acc[mt][tn][reg], -t1); // == fl(2*acc - t1)
          if (v >= bs[s]) { bs[s] = v; bi[s] = cidx; }
        }
      }
    }
  }

  // ---- block argmax reduction (overlay scratch on Ash) ----
  __syncthreads(); // all LDS A-reads complete
  float* red_s = (float*)Ash;      // [64][4]
  int* red_i = (int*)Ash + RB * 4; // [64][4]
  #pragma unroll
  for (int t = 0; t < 16; ++t) {
    float s = bs[t];
    int ii = bi[t];
    #pragma unroll
    for (int mask = 1; mask <= 8; mask <<= 1) {
      float os = __shfl_xor(s, mask, 64);
      int oi = __shfl_xor(ii, mask, 64);
      if (os > s || (os == s && oi < ii)) { s = os; ii = oi; }
    }
    if (l15 == 0) {
      int rloc = (t >> 2) * 16 + q * 4 + (t & 3); // mt*16 + q*4 + reg
      red_s[rloc * 4 + wn] = s;
      red_i[rloc * 4 + wn] = ii;
    }
  }
  __syncthreads();
  if (tid < RB) {
    float s0 = red_s[tid * 4];
    int i0 = red_i[tid * 4];
    #pragma unroll
    for (int x = 1; x < 4; ++x) {
      float sx = red_s[tid * 4 + x];
      int ix = red_i[tid * 4 + x];
      if (sx > s0 || (sx == s0 && ix < i0)) { s0 = sx; i0 = ix; }
    }
    partial_s[(size_t)(rowBase + tid) * CS + cs] = s0;
    partial_i[(size_t)(rowBase + tid) * CS + cs] = i0;
  }
}

// ---------------------------------------------------------------------------
// Combine col-split partials -> code; resid -= W[c]; quantized += W[c];
// new rr; Aext row for next head.
__global__ __launch_bounds__(64) void reduce_update_kernel(const float* __restrict__ embh,
                                                           float* __restrict__ resid,
                                                           float* __restrict__ rr,
                                                           const float* __restrict__ ps,
                                                           const int* __restrict__ pi,
                                                           float* __restrict__ out,
                                                           _Float16* __restrict__ Aext, int h) {
  int row = blockIdx.x;
  int lane = threadIdx.x;
  float bs = -INFINITY;
  int bi = 0x7fffffff;
  if (lane < CS) {
    bs = ps[(size_t)row * CS + lane];
    bi = pi[(size_t)row * CS + lane];
  }
  #pragma unroll
  for (int m = 8; m; m >>= 1) {
    float os = __shfl_xor(bs, m, 64);
    int oi = __shfl_xor(bi, m, 64);
    if (os > bs || (os == bs && oi < bi)) { bs = os; bi = oi; }
  }
  int c = __shfl(bi, 0, 64);
  if (lane == 0) out[NB + NB * ND + row * NH + h] = (float)c; // codes as f32

  const float* wv = embh + (size_t)c * ND;
  float q0 = wv[lane], q1 = wv[lane + 64];
  float r0 = resid[row * ND + lane] - q0;
  float r1 = resid[row * ND + lane + 64] - q1;
  resid[row * ND + lane] = r0;
  resid[row * ND + lane + 64] = r1;
  out[NB + row * ND + lane] += q0;
  out[NB + row * ND + lane + 64] += q1;

  // Aext row for the next head (harmless extra work on the last head)
  _Float16 h0 = (_Float16)r0, l0 = (_Float16)(r0 - (float)h0);
  _Float16 h1 = (_Float16)r1, l1 = (_Float16)(r1 - (float)h1);
  _Float16* ab = Aext + (size_t)row * KA;
  ab[lane] = h0;       ab[lane + 64] = h1;       // rh
  ab[128 + lane] = l0; ab[128 + lane + 64] = l1; // rl

  float s = r0 * r0 + r1 * r1;
  #pragma unroll
  for (int m = 32; m; m >>= 1) s += __shfl_xor(s, m, 64);
  if (lane == 0) rr[row] = s;
}

// ---------------------------------------------------------------------------
extern "C" void kernel_launch(void* const* d_in, const int* in_sizes, int n_in,
                              void* d_out, int out_size, void* d_ws, size_t ws_size,
                              hipStream_t stream) {
  const float* inp = (const float*)d_in[0]; // (4096,1,128)
  const float* emb = (const float*)d_in[1]; // (3,32768,128)
  float* out = (float*)d_out;               // loss | quantized | codes

  float* resid = (float*)d_ws;                        // NB*ND f32
  float* rr = resid + NB * ND;                        // NB
  float* norms = rr + NB;                             // NH*NK
  float* ps = norms + NH * NK;                        // NB*CS f32
  int* pi = (int*)(ps + (size_t)NB * CS);             // NB*CS i32
  _Float16* Aext = (_Float16*)(pi + (size_t)NB * CS); // NB*KA f16
  _Float16* Bext = Aext + (size_t)NB * KA;            // NH*NK*KB f16 (~100 MB)

  hipLaunchKernelGGL(init_kernel, dim3(NB), dim3(64), 0, stream, inp, resid, rr, out, Aext);
  hipLaunchKernelGGL(norms_kernel, dim3(NH * NK / 4), dim3(256), 0, stream, emb, norms);
  hipLaunchKernelGGL(split_w_all_kernel, dim3(NH * NK / 16), dim3(256), 0, stream, emb, Bext);
  for (int h = 0; h < NH; ++h) {
    hipLaunchKernelGGL(score_mfma_kernel, dim3((NB / RB) * CS), dim3(256), 0, stream,
                       Aext, Bext + (size_t)h * NK * KB, rr, norms + (size_t)h * NK, ps, pi);
    hipLaunchKernelGGL(reduce_update_kernel, dim3(NB), dim3(64), 0, stream,
                       emb + (size_t)h * NK * ND, resid, rr, ps, pi, out, Aext, h);
  }
}